// Round 4
// baseline (613.444 us; speedup 1.0000x reference)
//
#include <hip/hip_runtime.h>
#include <hip/hip_bf16.h>
#include <math.h>

#define B_ 16
#define L_ 32768
#define H_ 64
#define N_ 16
#define DM_ 32
#define T_ 128
#define C_ 256   /* L_/T_ */
#define TS_ 16   /* subtile rows */
#define MSTR_ 34 /* myu row stride (2-way bank aliasing = free) */
#define NL_ 8    /* modes per lane (N_/2) */

typedef __attribute__((ext_vector_type(8))) short short8;
typedef __attribute__((ext_vector_type(4))) float floatx4;
typedef unsigned short ushort_t;

// gelu matching jax.nn.gelu(approximate=True)
__device__ __forceinline__ float fast_gelu(float v) {
    float z = fmaf(0.044715f * v, v * v, v) * 0.7978845608028654f;
#if __has_builtin(__builtin_amdgcn_exp2f) && __has_builtin(__builtin_amdgcn_rcpf)
    float e = __builtin_amdgcn_exp2f(z * 2.8853900817779268f);
    float t = 1.0f - 2.0f * __builtin_amdgcn_rcpf(e + 1.0f);
#else
    float t = tanhf(z);
#endif
    return 0.5f * v * (1.0f + t);
}

__device__ __forceinline__ unsigned short bf16_rne(float f) {
    unsigned u = __float_as_uint(f);
    return (unsigned short)((u + 0x7FFFu + ((u >> 16) & 1u)) >> 16);
}
__device__ __forceinline__ float bf16_tof(unsigned short h) {
    return __uint_as_float(((unsigned)h) << 16);
}
// split 8 floats into bf16 hi + bf16 lo fragments (packed)
__device__ __forceinline__ void cvt8(const float* f, short8* hi, short8* lo) {
    union { unsigned u[4]; short8 s; } Hh, Ll;
    #pragma unroll
    for (int jp = 0; jp < 4; ++jp) {
        unsigned short h0 = bf16_rne(f[2*jp]), h1 = bf16_rne(f[2*jp+1]);
        Hh.u[jp] = (unsigned)h0 | ((unsigned)h1 << 16);
        float l0 = f[2*jp]   - bf16_tof(h0);
        float l1 = f[2*jp+1] - bf16_tof(h1);
        Ll.u[jp] = (unsigned)bf16_rne(l0) | ((unsigned)bf16_rne(l1) << 16);
    }
    *hi = Hh.s; *lo = Ll.s;
}

// ---------------- fused prep: film MLP | SSM coefs | W fragment table ------
__global__ void prep_kernel(const float* __restrict__ cp,
    const float* __restrict__ W0, const float* __restrict__ b0,
    const float* __restrict__ W1, const float* __restrict__ b1,
    const float* __restrict__ W2, const float* __restrict__ b2,
    const float* __restrict__ Wfilm, const float* __restrict__ bfilm,
    const float* __restrict__ W_lin,
    const float* __restrict__ log_dt,
    const float* __restrict__ A_re, const float* __restrict__ A_im,
    const float* __restrict__ C_re, const float* __restrict__ C_im,
    float* __restrict__ film, float* __restrict__ coef, ushort_t* __restrict__ gWf) {
    int tid = threadIdx.x;
    if (blockIdx.x == 0) {
        __shared__ float ca[B_][DM_];
        __shared__ float cb[B_][DM_];
        int b = tid >> 4, jj = tid & 15;
        #pragma unroll
        for (int t = 0; t < 2; ++t) {
            int j = jj + 16*t;
            float acc = fmaf(cp[b*2+0], W0[j], fmaf(cp[b*2+1], W0[DM_+j], b0[j]));
            ca[b][j] = fast_gelu(acc);
        }
        __syncthreads();
        #pragma unroll
        for (int t = 0; t < 2; ++t) {
            int j = jj + 16*t;
            float acc = b1[j];
            #pragma unroll
            for (int i = 0; i < DM_; ++i) acc = fmaf(ca[b][i], W1[i*DM_+j], acc);
            cb[b][j] = fast_gelu(acc);
        }
        __syncthreads();
        float c2[2];
        #pragma unroll
        for (int t = 0; t < 2; ++t) {
            int j = jj + 16*t;
            float acc = b2[j];
            #pragma unroll
            for (int i = 0; i < DM_; ++i) acc = fmaf(cb[b][i], W2[i*DM_+j], acc);
            c2[t] = fast_gelu(acc);
        }
        __syncthreads();
        #pragma unroll
        for (int t = 0; t < 2; ++t) ca[b][jj+16*t] = c2[t];
        __syncthreads();
        #pragma unroll
        for (int t = 0; t < 8; ++t) {
            int k = jj + 16*t;
            float a = bfilm[k];
            #pragma unroll
            for (int i = 0; i < DM_; ++i) a = fmaf(ca[b][i], Wfilm[i*2*H_+k], a);
            film[b*2*H_ + k] = a;
        }
    } else if (blockIdx.x == 1) {
        for (int it = 0; it < 4; ++it) {
            int g = tid + 256*it;
            int h = g >> 4, n = g & 15;
            float dt = expf(log_dt[h]);
            float Ar = A_re[h*N_+n], Ai = A_im[h*N_+n];
            float ar = dt*Ar, ai = dt*Ai;
            float er = expf(ar);
            float wr = er * cosf(ai), wi = er * sinf(ai);
            float eT = expf((float)T_ * ar);
            float aT = (float)T_ * ai;
            float wTr = eT * cosf(aT), wTi = eT * sinf(aT);
            float d  = Ar*Ar + Ai*Ai;
            float nr = wr - 1.0f, ni = wi;
            float qr = (nr*Ar + ni*Ai) / d;
            float qi = (ni*Ar - nr*Ai) / d;
            float Cr = C_re[h*N_+n], Ci = C_im[h*N_+n];
            float cr = 2.0f * (Cr*qr - Ci*qi);
            float ci = 2.0f * (Cr*qi + Ci*qr);
            coef[(n*6+0)*H_+h] = wr;
            coef[(n*6+1)*H_+h] = wi;
            coef[(n*6+2)*H_+h] = wTr;
            coef[(n*6+3)*H_+h] = wTi;
            coef[(n*6+4)*H_+h] = cr;
            coef[(n*6+5)*H_+h] = ci;
        }
    } else {
        int lane = tid & 63, grp = tid >> 6;
        int m = lane & 15, quad = lane >> 4;
        for (int f = grp*4; f < grp*4 + 4; ++f) {
            int t = f >> 3, kt = (f >> 2) & 1, nt = f & 3;
            float fv[8];
            #pragma unroll
            for (int j = 0; j < 8; ++j)
                fv[j] = W_lin[(kt*32 + quad*8 + j)*H_ + nt*16 + m];
            short8 hi, lo;
            cvt8(fv, &hi, &lo);
            ((short8*)gWf)[f*64 + lane] = t ? lo : hi;
        }
    }
}

// ---- phase 2a: per-group(16 chunks) aggregate A_g = sum wT^(15-i) v_i ----
__global__ void scan2a_kernel(const float* __restrict__ states,
                              const float* __restrict__ coef,
                              float* __restrict__ agg) {
    int t = blockIdx.x*256 + threadIdx.x;     // 262144 = b*n*g*h
    int h = t & 63, n = (t >> 6) & 15, g = (t >> 10) & 15, b = t >> 14;
    float wTr = coef[(n*6+2)*H_+h], wTi = coef[(n*6+3)*H_+h];
    const float2* S = (const float2*)states + ((size_t)(b*C_ + g*16)*N_ + n)*H_ + h;
    float2 v[16];
    #pragma unroll
    for (int i = 0; i < 16; ++i) v[i] = S[(size_t)i*N_*H_];
    float Ar = 0.f, Ai = 0.f;
    #pragma unroll
    for (int i = 0; i < 16; ++i) {
        float nr = fmaf(wTr, Ar, fmaf(-wTi, Ai, v[i].x));
        float ni = fmaf(wTr, Ai, fmaf( wTi, Ar, v[i].y));
        Ar = nr; Ai = ni;
    }
    ((float2*)agg)[((size_t)(b*16 + g)*N_ + n)*H_ + h] = make_float2(Ar, Ai);
}

// ---- phase 2b: 16-group prefix with wT^16 (in-place on agg) ----
__global__ void scan2b_kernel(float* __restrict__ agg,
                              const float* __restrict__ coef) {
    int t = blockIdx.x*256 + threadIdx.x;     // 16384 = b*n*h
    int h = t & 63, n = (t >> 6) & 15, b = t >> 10;
    float wr = coef[(n*6+2)*H_+h], wi = coef[(n*6+3)*H_+h];
    #pragma unroll
    for (int s = 0; s < 4; ++s) {             // wT^16 by squaring
        float r2 = wr*wr - wi*wi, i2 = 2.f*wr*wi;
        wr = r2; wi = i2;
    }
    float2* A = (float2*)agg + (size_t)b*16*N_*H_ + (size_t)n*H_ + h;
    float2 v[16];
    #pragma unroll
    for (int g = 0; g < 16; ++g) v[g] = A[(size_t)g*N_*H_];
    float Pr = 0.f, Pi = 0.f;
    #pragma unroll
    for (int g = 0; g < 16; ++g) {
        A[(size_t)g*N_*H_] = make_float2(Pr, Pi);
        float nr = fmaf(wr, Pr, fmaf(-wi, Pi, v[g].x));
        float ni = fmaf(wr, Pi, fmaf( wi, Pr, v[g].y));
        Pr = nr; Pi = ni;
    }
}

// ---- phase 2c: replay within group, write state-at-chunk-start ----
__global__ void scan2c_kernel(float* __restrict__ states,
                              const float* __restrict__ coef,
                              const float* __restrict__ agg) {
    int t = blockIdx.x*256 + threadIdx.x;     // 262144
    int h = t & 63, n = (t >> 6) & 15, g = (t >> 10) & 15, b = t >> 14;
    float wTr = coef[(n*6+2)*H_+h], wTi = coef[(n*6+3)*H_+h];
    float2* S = (float2*)states + ((size_t)(b*C_ + g*16)*N_ + n)*H_ + h;
    float2 P = ((const float2*)agg)[((size_t)(b*16 + g)*N_ + n)*H_ + h];
    float2 v[16];
    #pragma unroll
    for (int i = 0; i < 16; ++i) v[i] = S[(size_t)i*N_*H_];
    float Pr = P.x, Pi = P.y;
    #pragma unroll
    for (int i = 0; i < 16; ++i) {
        S[(size_t)i*N_*H_] = make_float2(Pr, Pi);
        float nr = fmaf(wTr, Pr, fmaf(-wTi, Pi, v[i].x));
        float ni = fmaf(wTr, Pi, fmaf( wTi, Pr, v[i].y));
        Pr = nr; Pi = ni;
    }
}

// ---------------- phases 1 & 3: MFMA GEMM + lane-pair-split scan -----------
// One wave per (chunk, h-half). lane = 2*h_local + n_half; each lane keeps
// NL_=8 modes (48 persistent VGPRs). Wave computes its own nt-half of the
// GEMM -> u for its 32 h's -> private LDS transpose -> scan. Zero barriers
// in the main loop; y combined across the lane pair with one shfl_xor.
template<int PHASE>
__global__ __launch_bounds__(512, PHASE == 1 ? 6 : 4)
void gemm_scan_kernel(const float* __restrict__ x,
                      const ushort_t* __restrict__ gWf,
                      const float* __restrict__ b_lin,
                      const float* __restrict__ coef, float* __restrict__ states,
                      const float* __restrict__ D, const float* __restrict__ film,
                      float* __restrict__ out) {
    __shared__ short8 Wf[16*64];              // 16 KB
    __shared__ float  myu[8][TS_*MSTR_];      // 8 * 2176 B
    const int tid  = threadIdx.x;
    const int lane = tid & 63;
    const int wv   = tid >> 6;                // 0..7
    const int q    = blockIdx.x*4 + (wv >> 1);  // chunk 0..4095
    const int wh   = wv & 1;                  // h-half
    const int b    = q >> 8;
    const int c    = q & 255;
    const int hl   = lane >> 1;               // local h 0..31
    const int h    = wh*32 + hl;              // global h
    const int j    = lane & 1;                // n-half
    const int m    = lane & 15;
    const int quad = lane >> 4;

    // stage Wf table (1024 short8, 512 threads -> 2 each), single barrier
    Wf[tid]       = ((const short8*)gWf)[tid];
    Wf[tid + 512] = ((const short8*)gWf)[tid + 512];
    __syncthreads();

    float wr[NL_], wi[NL_], sr[NL_], si[NL_];
    float cr[NL_], ci[NL_];
    float g_ = 0.f, be_ = 0.f, Dh = 0.f;
    #pragma unroll
    for (int nn = 0; nn < NL_; ++nn) {
        int n = j*NL_ + nn;
        wr[nn] = coef[(n*6+0)*H_ + h];
        wi[nn] = coef[(n*6+1)*H_ + h];
    }
    if (PHASE == 1) {
        #pragma unroll
        for (int nn = 0; nn < NL_; ++nn) { sr[nn] = 0.f; si[nn] = 0.f; }
    } else {
        #pragma unroll
        for (int nn = 0; nn < NL_; ++nn) {
            int n = j*NL_ + nn;
            cr[nn] = coef[(n*6+4)*H_ + h];
            ci[nn] = coef[(n*6+5)*H_ + h];
            float2 s0 = ((const float2*)states)[((size_t)q*N_ + n)*H_ + h];
            sr[nn] = s0.x; si[nn] = s0.y;
        }
        g_  = film[b*2*H_ + h];
        be_ = film[b*2*H_ + H_ + h];
        Dh  = D[h];
    }
    float blv[2];
    #pragma unroll
    for (int ntl = 0; ntl < 2; ++ntl) blv[ntl] = b_lin[(2*wh + ntl)*16 + m];

    const float* xp = x + ((size_t)b*L_ + (size_t)c*T_)*H_;
    float* op = out + ((size_t)b*L_ + (size_t)c*T_)*H_;
    const float* a0 = xp + m*H_ + quad*8;     // A-frag source for this lane
    float* myw = myu[wv];

    // prefetch subtile 0
    float4 p00 = *(const float4*)(a0);
    float4 p01 = *(const float4*)(a0 + 4);
    float4 p10 = *(const float4*)(a0 + 32);
    float4 p11 = *(const float4*)(a0 + 36);

    for (int s = 0; s < T_/TS_; ++s) {
        // convert current subtile frags FIRST (frees p regs), then prefetch
        short8 ah[2], al[2];
        {
            float f0[8] = {p00.x,p00.y,p00.z,p00.w,p01.x,p01.y,p01.z,p01.w};
            cvt8(f0, &ah[0], &al[0]);
            float f1[8] = {p10.x,p10.y,p10.z,p10.w,p11.x,p11.y,p11.z,p11.w};
            cvt8(f1, &ah[1], &al[1]);
        }
        if (s < T_/TS_ - 1) {
            const float* nx = a0 + (size_t)(s+1)*TS_*H_;
            p00 = *(const float4*)(nx);
            p01 = *(const float4*)(nx + 4);
            p10 = *(const float4*)(nx + 32);
            p11 = *(const float4*)(nx + 36);
        }
        // GEMM: this wave's nt pair (its own 32 h's); u -> private LDS tile
        #pragma unroll
        for (int ntl = 0; ntl < 2; ++ntl) {
            int nt = 2*wh + ntl;
            floatx4 acc = {0.f, 0.f, 0.f, 0.f};
            #pragma unroll
            for (int kt = 0; kt < 2; ++kt) {
                short8 bh = Wf[(kt*4 + nt)*64 + lane];
                short8 bl = Wf[((2+kt)*4 + nt)*64 + lane];
                acc = __builtin_amdgcn_mfma_f32_16x16x32_bf16(ah[kt], bh, acc, 0, 0, 0);
                acc = __builtin_amdgcn_mfma_f32_16x16x32_bf16(al[kt], bh, acc, 0, 0, 0);
                acc = __builtin_amdgcn_mfma_f32_16x16x32_bf16(ah[kt], bl, acc, 0, 0, 0);
            }
            #pragma unroll
            for (int r = 0; r < 4; ++r)
                myw[(quad*4 + r)*MSTR_ + ntl*16 + m] = fast_gelu(acc[r] + blv[ntl]);
        }
        // scan TS_ rows; lane-pair n-split (own-wave DS ordering, no barrier)
        for (int l = 0; l < TS_; ++l) {
            float uv = myu[wv][l*MSTR_ + hl];   // pair-broadcast read
            if (PHASE == 1) {
                #pragma unroll
                for (int nn = 0; nn < NL_; ++nn) {
                    float nr = fmaf(wr[nn], sr[nn], fmaf(-wi[nn], si[nn], uv));
                    float ni = fmaf(wr[nn], si[nn], wi[nn]*sr[nn]);
                    sr[nn] = nr; si[nn] = ni;
                }
            } else {
                float y0 = 0.f, y1 = 0.f;
                #pragma unroll
                for (int nn = 0; nn < NL_; ++nn) {
                    float nr = fmaf(wr[nn], sr[nn], fmaf(-wi[nn], si[nn], uv));
                    float ni = fmaf(wr[nn], si[nn], wi[nn]*sr[nn]);
                    sr[nn] = nr; si[nn] = ni;
                    y0 = fmaf(cr[nn], nr, y0);
                    y1 = fmaf(ci[nn], ni, y1);
                }
                float yp = y0 - y1;
                float y  = yp + __shfl_xor(yp, 1, 64);   // combine n-halves
                float xg = xp[(s*TS_ + l)*H_ + h];       // L1/L2 hit (gate)
                float yv = fmaf(Dh, uv, y);
                float res = xg * fast_gelu(fmaf(yv, g_, be_));
                if (j == 0)
                    __builtin_nontemporal_store(res, &op[(s*TS_ + l)*H_ + h]);
            }
        }
    }
    if (PHASE == 1) {
        #pragma unroll
        for (int nn = 0; nn < NL_; ++nn) {
            int n = j*NL_ + nn;
            ((float2*)states)[((size_t)q*N_ + n)*H_ + h] = make_float2(sr[nn], si[nn]);
        }
    }
}

extern "C" void kernel_launch(void* const* d_in, const int* in_sizes, int n_in,
                              void* d_out, int out_size, void* d_ws, size_t ws_size,
                              hipStream_t stream) {
    const float* x     = (const float*)d_in[0];
    const float* cp    = (const float*)d_in[1];
    const float* W0    = (const float*)d_in[2];
    const float* b0    = (const float*)d_in[3];
    const float* W1    = (const float*)d_in[4];
    const float* b1    = (const float*)d_in[5];
    const float* W2    = (const float*)d_in[6];
    const float* b2    = (const float*)d_in[7];
    const float* W_lin = (const float*)d_in[8];
    const float* b_lin = (const float*)d_in[9];
    const float* log_dt= (const float*)d_in[10];
    const float* A_re  = (const float*)d_in[11];
    const float* A_im  = (const float*)d_in[12];
    const float* C_re  = (const float*)d_in[13];
    const float* C_im  = (const float*)d_in[14];
    const float* D     = (const float*)d_in[15];
    const float* W_f   = (const float*)d_in[16];
    const float* b_f   = (const float*)d_in[17];
    float* out = (float*)d_out;

    float*    film   = (float*)d_ws;                // 2048 floats
    float*    coef   = film + B_*2*H_;              // 6144 floats
    ushort_t* gWf    = (ushort_t*)(coef + 6*H_*N_); // 8192 ushorts (16 KB)
    float*    states = (float*)(gWf + 16*64*8);     // B*C*N*H*2 = 8.4M floats
    float*    agg    = states + (size_t)B_*C_*N_*H_*2;  // B*16*N*H*2 = 0.5M floats

    prep_kernel<<<3, 256, 0, stream>>>(cp, W0, b0, W1, b1, W2, b2, W_f, b_f,
                                       W_lin, log_dt, A_re, A_im, C_re, C_im,
                                       film, coef, gWf);
    gemm_scan_kernel<1><<<(B_*C_)/4, 512, 0, stream>>>(
        x, gWf, b_lin, coef, states, nullptr, nullptr, nullptr);
    scan2a_kernel<<<1024, 256, 0, stream>>>(states, coef, agg);
    scan2b_kernel<<<64, 256, 0, stream>>>(agg, coef);
    scan2c_kernel<<<1024, 256, 0, stream>>>(states, coef, agg);
    gemm_scan_kernel<3><<<(B_*C_)/4, 512, 0, stream>>>(
        x, gWf, b_lin, coef, states, D, film, out);
}